// Round 17
// baseline (78.475 us; speedup 1.0000x reference)
//
#include <hip/hip_runtime.h>
#include <math.h>

typedef _Float16 f16;
typedef _Float16 f16x8 __attribute__((ext_vector_type(8)));
typedef _Float16 f16x4 __attribute__((ext_vector_type(4)));
typedef float f32x4 __attribute__((ext_vector_type(4)));

#define BATCH 8
#define CHN   64
#define NPTS  8192
#define P2    192
#define GG    (P2 * P2)   // 36864
#define NCHG  32          // gram chunks per batch (256 pts each)

// ---------------------------------------------------------------------------
// k_w (R15): blocks 0-3: P[h][o][c2]; blocks 4-195: MX[p][q2][h] (f32).
// All weight reads staged coalesced into LDS first.
// ---------------------------------------------------------------------------
__global__ __launch_bounds__(256) void k_w(const float* __restrict__ Wq,
                                           const float* __restrict__ Wk,
                                           const float* __restrict__ Wv,
                                           const float* __restrict__ Wout,
                                           float* __restrict__ P,
                                           float* __restrict__ MX) {
    __shared__ float WL[16384 + 256];
    const int blk = blockIdx.x;
    const int tid = threadIdx.x;

    if (blk < 4) {
        const int h = blk;
        float* WoutL = WL;               // [o][d] 64x64
        float* WvL   = WL + 4096;        // [d][c2] 64x64
        for (int i = tid; i < 4096; i += 256) {
            int r = i >> 6, cd = i & 63;
            WoutL[i] = Wout[r * 256 + h * 64 + cd];
            WvL[i]   = Wv[(h * 64 + r) * 64 + cd];
        }
        __syncthreads();
        for (int e = 0; e < 16; e++) {
            int id = e * 256 + tid;
            int r = id >> 6, c2 = id & 63;
            float s = 0.0f;
#pragma unroll 8
            for (int d = 0; d < 64; d++)
                s += WoutL[r * 64 + d] * WvL[d * 64 + c2];
            P[h * 4096 + id] = s;
        }
    } else {
        const int p = blk - 4;           // 0..191
        const int c = p / 3;
        float* WkL   = WL;               // full Wk [256][64]
        float* WqCol = WL + 16384;       // [h*64+d]
        for (int i = tid; i < 16384; i += 256)
            WkL[i] = Wk[i];
        if (tid < 256)
            WqCol[tid] = Wq[tid * 64 + c];
        __syncthreads();
        if (tid < P2) {
            const int q2 = tid, c2 = q2 / 3;
            f32x4 v;
#pragma unroll
            for (int h = 0; h < 4; h++) {
                float s = 0.0f;
#pragma unroll 8
                for (int d = 0; d < 64; d++)
                    s += WqCol[h * 64 + d] * WkL[(h * 64 + d) * 64 + c2];
                v[h] = s;
            }
            *(f32x4*)(MX + ((size_t)p * P2 + q2) * 4) = v;
        }
    }
}

// ---------------------------------------------------------------------------
// k_gram (R15/R7, proven): K=256 pts per block, 8 waves (48x96 strips),
// 4 x 64-pt phases, double-buffered LDS, logit-contraction epilogue. grid 256.
// IDEMPOTENT (plain stores) — launched twice this round as a diagnostic.
// ---------------------------------------------------------------------------
__global__ __launch_bounds__(512, 2) void k_gram(const float* __restrict__ feat,
                                                 const f32x4* __restrict__ MX,
                                                 float* __restrict__ pl) {
    const int kc  = blockIdx.x & (NCHG - 1);
    const int b   = blockIdx.x >> 5;
    const int n0  = kc * 256;
    const int tid = threadIdx.x;
    const int wid = tid >> 6, lane = tid & 63;
    const int l15 = lane & 15, l4 = lane >> 4;
    const int qd = wid & 3, strip = wid >> 2;
    const int qp = (qd >> 1) * 96 + strip * 48;
    const int qq = (qd & 1) * 96;

    __shared__ char smem[77184];
    __shared__ float fin[8][36];
    char* T0 = smem;
    char* T1 = smem + 24576;
    float (*SRED)[36][67] = (float (*)[36][67])smem;

    const float* fb = feat + (size_t)b * CHN * NPTS * 3;
    const int tc = tid >> 4;
    const int g4 = (tid & 15) * 4;
    const int g8 = (tid & 15) * 8;

    f32x4 acc[3][6];
#pragma unroll
    for (int i = 0; i < 3; i++)
#pragma unroll
        for (int j = 0; j < 6; j++) acc[i][j] = (f32x4){0.f, 0.f, 0.f, 0.f};

    float4 SA[2][3], SB[2][3];

#define G_LOADS(S, nbase)                                                      \
    {                                                                          \
        _Pragma("unroll")                                                      \
        for (int ti = 0; ti < 2; ti++) {                                       \
            int c = tc + ti * 32;                                              \
            const float* src = fb + ((size_t)c * NPTS + (nbase) + g4) * 3;     \
            S[ti][0] = *(const float4*)(src);                                  \
            S[ti][1] = *(const float4*)(src + 4);                              \
            S[ti][2] = *(const float4*)(src + 8);                              \
        }                                                                      \
    }
#define G_WRITES(S, Tb)                                                        \
    {                                                                          \
        _Pragma("unroll")                                                      \
        for (int ti = 0; ti < 2; ti++) {                                       \
            int c = tc + ti * 32;                                              \
            float v[12] = {S[ti][0].x, S[ti][0].y, S[ti][0].z, S[ti][0].w,     \
                           S[ti][1].x, S[ti][1].y, S[ti][1].z, S[ti][1].w,     \
                           S[ti][2].x, S[ti][2].y, S[ti][2].z, S[ti][2].w};    \
            _Pragma("unroll")                                                  \
            for (int t = 0; t < 3; t++) {                                      \
                int row = c * 3 + t;                                           \
                f16x4 pk = {(f16)v[t], (f16)v[3 + t], (f16)v[6 + t],           \
                            (f16)v[9 + t]};                                    \
                int bo = (row * 128 + g8) ^ ((row & 7) << 4);                  \
                *(f16x4*)((Tb) + bo) = pk;                                     \
            }                                                                  \
        }                                                                      \
    }
#define G_COMPUTE(Tb)                                                          \
    {                                                                          \
        _Pragma("unroll")                                                      \
        for (int ks = 0; ks < 2; ks++) {                                       \
            f16x8 af[3], bf[6];                                                \
            _Pragma("unroll")                                                  \
            for (int mt = 0; mt < 3; mt++) {                                   \
                int row = qp + mt * 16 + l15;                                  \
                af[mt] = *(const f16x8*)((Tb) +                                \
                    ((row * 128 + ks * 64 + l4 * 16) ^ ((row & 7) << 4)));     \
            }                                                                  \
            _Pragma("unroll")                                                  \
            for (int nt = 0; nt < 6; nt++) {                                   \
                int row = qq + nt * 16 + l15;                                  \
                bf[nt] = *(const f16x8*)((Tb) +                                \
                    ((row * 128 + ks * 64 + l4 * 16) ^ ((row & 7) << 4)));     \
            }                                                                  \
            _Pragma("unroll")                                                  \
            for (int mt = 0; mt < 3; mt++)                                     \
                _Pragma("unroll")                                              \
                for (int nt = 0; nt < 6; nt++)                                 \
                    acc[mt][nt] = __builtin_amdgcn_mfma_f32_16x16x32_f16(      \
                        af[mt], bf[nt], acc[mt][nt], 0, 0, 0);                 \
        }                                                                      \
    }

    G_LOADS(SA, n0);
    G_WRITES(SA, T0);
    G_LOADS(SB, n0 + 64);
    __syncthreads();
    G_COMPUTE(T0); G_WRITES(SB, T1); G_LOADS(SA, n0 + 128);
    __syncthreads();
    G_COMPUTE(T1); G_WRITES(SA, T0); G_LOADS(SB, n0 + 192);
    __syncthreads();
    G_COMPUTE(T0); G_WRITES(SB, T1);
    __syncthreads();
    G_COMPUTE(T1);
    __syncthreads();

    float l[36];
#pragma unroll
    for (int i = 0; i < 36; i++) l[i] = 0.0f;
#pragma unroll
    for (int mt = 0; mt < 3; mt++) {
#pragma unroll
        for (int r = 0; r < 4; r++) {
            int p = qp + mt * 16 + l4 * 4 + r;
            const f32x4* mxp = MX + (size_t)p * P2 + qq + l15;
#pragma unroll
            for (int nt = 0; nt < 6; nt++) {
                f32x4 ms = mxp[nt * 16];
                float g = acc[mt][nt][r];
                const int ts = ((mt + r) % 3) * 3 + (nt % 3);
                l[ts]      = fmaf(ms[0], g, l[ts]);
                l[9 + ts]  = fmaf(ms[1], g, l[9 + ts]);
                l[18 + ts] = fmaf(ms[2], g, l[18 + ts]);
                l[27 + ts] = fmaf(ms[3], g, l[27 + ts]);
            }
        }
    }
    const int pt = l4 % 3, ps = l15 % 3;
    int rowmap[9];
#pragma unroll
    for (int tt = 0; tt < 3; tt++)
#pragma unroll
        for (int ss = 0; ss < 3; ss++)
            rowmap[tt * 3 + ss] = ((tt + pt) % 3) * 3 + ((ss + ps) % 3);
#pragma unroll
    for (int h = 0; h < 4; h++)
#pragma unroll
        for (int i9 = 0; i9 < 9; i9++)
            SRED[wid][h * 9 + rowmap[i9]][lane] = l[h * 9 + i9];
    __syncthreads();
    if (tid < 288) {
        int w = tid / 36, row = tid - (tid / 36) * 36;
        float s = 0.0f;
#pragma unroll 8
        for (int col = 0; col < 64; col++) s += SRED[w][row][col];
        fin[w][row] = s;
    }
    __syncthreads();
    if (tid < 36) {
        float s = 0.0f;
#pragma unroll
        for (int w = 0; w < 8; w++) s += fin[w][tid];
        pl[(size_t)(b * NCHG + kc) * 36 + tid] = s;
    }
#undef G_LOADS
#undef G_WRITES
#undef G_COMPUTE
}

// ---------------------------------------------------------------------------
// k_abig: fused softmax + Ab build, identity folded.  (R15, unchanged)
// ---------------------------------------------------------------------------
__global__ __launch_bounds__(256) void k_abig(const float* __restrict__ pl,
                                              const float* __restrict__ P,
                                              f16* __restrict__ Ab) {
    const int blk = blockIdx.x;                // 1152 = 8 b x 144
    const int b   = blk / 144;
    const int tid = threadIdx.x;
    __shared__ float ls[36], wsm[36];
    if (tid < 36) {
        float s = 0.0f;
        for (int k = 0; k < NCHG; k++)
            s += pl[(size_t)(b * NCHG + k) * 36 + tid];
        ls[tid] = s * 0.07216878364870322f;    // 1/sqrt(192)
    }
    __syncthreads();
    if (tid < 36) {
        int base = (tid / 3) * 3;
        float z0 = ls[base], z1 = ls[base + 1], z2 = ls[base + 2];
        float mx = fmaxf(z0, fmaxf(z1, z2));
        float e0 = expf(z0 - mx), e1 = expf(z1 - mx), e2 = expf(z2 - mx);
        wsm[tid] = expf(ls[tid] - mx) / (e0 + e1 + e2);
    }
    __syncthreads();

    int i  = blk * 256 + tid;
    int rr = i - b * GG;
    int p2 = rr / P2, q2 = rr - p2 * P2;
    int o = p2 / 3, t = p2 - 3 * (p2 / 3);
    int c = q2 / 3, s = q2 - 3 * (q2 / 3);
    float acc = (p2 == q2) ? 1.0f : 0.0f;      // identity folded
#pragma unroll
    for (int h = 0; h < 4; h++)
        acc = fmaf(wsm[h * 9 + t * 3 + s], P[h * 4096 + o * 64 + c], acc);
    Ab[i] = (f16)acc;
}

// ---------------------------------------------------------------------------
// k_apply v5 (ground-truth ~19.7 us): out = (I+Abig)*X via LDS out-tile,
// epilogue in two 32-pt rounds, LDS 25.6 KB. grid 1024.  (R15, unchanged)
// ---------------------------------------------------------------------------
__global__ __launch_bounds__(256, 4) void k_apply(const float* __restrict__ feat,
                                                  const f16* __restrict__ Ab,
                                                  float* __restrict__ out) {
    const int nb  = blockIdx.x & 127;
    const int b   = blockIdx.x >> 7;
    const int n0  = nb * 64;
    const int tid = threadIdx.x;
    const int wid = tid >> 6, lane = tid & 63;
    const int l15 = lane & 15, l4 = lane >> 4;

    __shared__ char lds[25600];          // X: 64 x 400B  then  OT-half: 64 x 400B

    const float* fb = feat + (size_t)b * CHN * NPTS * 3;
    const f16*   A  = Ab + (size_t)b * GG;
    float*       ob = out + (size_t)b * CHN * NPTS * 3;

    // ---- phase 0: stage X[nn][q2] fp16 (row stride 400 B) ----
    {
        float4 S[12];
#pragma unroll
        for (int i = 0; i < 12; i++) {
            int idx = tid + i * 256;
            int c = idx / 48, j = idx - (idx / 48) * 48;
            S[i] = *(const float4*)(fb + ((size_t)c * NPTS + n0) * 3 + j * 4);
        }
#pragma unroll
        for (int i = 0; i < 12; i++) {
            int idx = tid + i * 256;
            int c = idx / 48, j = idx - (idx / 48) * 48;
            float vv[4] = {S[i].x, S[i].y, S[i].z, S[i].w};
#pragma unroll
            for (int u = 0; u < 4; u++) {
                int e = j * 4 + u, nn = e / 3, s = e - 3 * (e / 3);
                *(f16*)(lds + nn * 400 + (c * 3 + s) * 2) = (f16)vv[u];
            }
        }
    }
    __syncthreads();

    // ---- phase 1: MFMA with 2-deep pipelined A-fragment loads ----
    f32x4 acc[3][4];
#pragma unroll
    for (int i = 0; i < 3; i++)
#pragma unroll
        for (int j = 0; j < 4; j++) acc[i][j] = (f32x4){0.f, 0.f, 0.f, 0.f};

    f16x8 afA[3], afB[3];
    const int prow = wid * 48 + l15;

#define LOAD_AF(dst, ks)                                                       \
    {                                                                          \
        _Pragma("unroll")                                                      \
        for (int mt = 0; mt < 3; mt++)                                         \
            dst[mt] = *(const f16x8*)(A + (size_t)(prow + mt * 16) * P2        \
                                        + (ks) * 32 + l4 * 8);                 \
    }
#define DO_MFMA(src, ks)                                                       \
    {                                                                          \
        f16x8 bf[4];                                                           \
        _Pragma("unroll")                                                      \
        for (int nt = 0; nt < 4; nt++) {                                       \
            int nl = nt * 16 + l15;                                            \
            bf[nt] = *(const f16x8*)(lds + nl * 400 + (ks) * 64 + l4 * 16);    \
        }                                                                      \
        _Pragma("unroll")                                                      \
        for (int mt = 0; mt < 3; mt++)                                         \
            _Pragma("unroll")                                                  \
            for (int nt = 0; nt < 4; nt++)                                     \
                acc[mt][nt] = __builtin_amdgcn_mfma_f32_16x16x32_f16(          \
                    src[mt], bf[nt], acc[mt][nt], 0, 0, 0);                    \
    }

    LOAD_AF(afA, 0);
    LOAD_AF(afB, 1); DO_MFMA(afA, 0);
    LOAD_AF(afA, 2); DO_MFMA(afB, 1);
    LOAD_AF(afB, 3); DO_MFMA(afA, 2);
    LOAD_AF(afA, 4); DO_MFMA(afB, 3);
    LOAD_AF(afB, 5); DO_MFMA(afA, 4);
    DO_MFMA(afB, 5);
#undef LOAD_AF
#undef DO_MFMA

    __syncthreads();                     // X dead; OT takes over the LDS

    // ---- phases 2+3, two rounds of 32 points each ----
#pragma unroll
    for (int rnd = 0; rnd < 2; rnd++) {
#pragma unroll
        for (int mt = 0; mt < 3; mt++) {
#pragma unroll
            for (int r = 0; r < 4; r++) {
                int p2 = wid * 48 + mt * 16 + l4 * 4 + r;
                int o = p2 / 3, t = p2 - 3 * (p2 / 3);
#pragma unroll
                for (int ntl = 0; ntl < 2; ntl++) {
                    int nnl = ntl * 16 + l15;
                    *(float*)(lds + o * 400 + (nnl * 3 + t) * 4)
                        = acc[mt][rnd * 2 + ntl][r];
                }
            }
        }
        __syncthreads();
#pragma unroll
        for (int k = 0; k < 6; k++) {
            int fid = k * 256 + tid;
            int o = fid / 24, w = fid - (fid / 24) * 24;
            float4 v = *(const float4*)(lds + o * 400 + w * 16);
            *(float4*)(ob + ((size_t)o * NPTS + n0 + rnd * 32) * 3 + w * 4) = v;
        }
        __syncthreads();
    }
}

extern "C" void kernel_launch(void* const* d_in, const int* in_sizes, int n_in,
                              void* d_out, int out_size, void* d_ws, size_t ws_size,
                              hipStream_t stream) {
    const float* feat = (const float*)d_in[0];
    const float* Wq   = (const float*)d_in[2];
    const float* Wk   = (const float*)d_in[3];
    const float* Wv   = (const float*)d_in[4];
    const float* Wout = (const float*)d_in[5];
    float* out = (float*)d_out;

    char* w8 = (char*)d_ws;                    // total ws use: ~1.3 MB
    f16*   Ab = (f16*)w8;                      //   589,824 B
    float* P  = (float*)(w8 + 589824);         //    65,536 B
    float* MX = (float*)(w8 + 655360);         //   589,824 B
    float* pl = (float*)(w8 + 1245184);        //    36,864 B

    k_w    <<<196,          256, 0, stream>>>(Wq, Wk, Wv, Wout, P, MX);
    // DIAGNOSTIC: k_gram launched TWICE (idempotent — plain stores of a pure
    // function of feat/MX). dur_us - 62.2 = gram marginal cost + 1 gap.
    k_gram <<<BATCH * NCHG, 512, 0, stream>>>(feat, (const f32x4*)MX, pl);
    k_gram <<<BATCH * NCHG, 512, 0, stream>>>(feat, (const f32x4*)MX, pl);
    k_abig <<<1152,         256, 0, stream>>>(pl, P, Ab);
    k_apply<<<1024,         256, 0, stream>>>(feat, Ab, out);
}

// Round 18
// 58.955 us; speedup vs baseline: 1.3311x; 1.3311x over previous
//
#include <hip/hip_runtime.h>
#include <math.h>

typedef _Float16 f16;
typedef _Float16 f16x8 __attribute__((ext_vector_type(8)));
typedef _Float16 f16x4 __attribute__((ext_vector_type(4)));
typedef float f32x4 __attribute__((ext_vector_type(4)));

#define BATCH 8
#define CHN   64
#define NPTS  8192
#define P2    192
#define GG    (P2 * P2)   // 36864
#define NCHG  32          // gram chunks per batch (256 pts each)

// ---------------------------------------------------------------------------
// k_w v3 (grid 8): blocks 0-3 (h=blk):  P[h][o][c2] = sum_d Wout*Wv   (f32)
//                  blocks 4-7 (h=blk-4): MS[c][c2][h] = f16(sum_d Wq*Wk)
// All weight reads staged coalesced into LDS.
// ---------------------------------------------------------------------------
__global__ __launch_bounds__(256) void k_w(const float* __restrict__ Wq,
                                           const float* __restrict__ Wk,
                                           const float* __restrict__ Wv,
                                           const float* __restrict__ Wout,
                                           float* __restrict__ P,
                                           f16* __restrict__ MS) {
    __shared__ float WL[8192];
    const int blk = blockIdx.x;
    const int tid = threadIdx.x;

    if (blk < 4) {
        const int h = blk;
        float* WoutL = WL;               // [o][d] 64x64
        float* WvL   = WL + 4096;        // [d][c2] 64x64
        for (int i = tid; i < 4096; i += 256) {
            int r = i >> 6, cd = i & 63;
            WoutL[i] = Wout[r * 256 + h * 64 + cd];
            WvL[i]   = Wv[(h * 64 + r) * 64 + cd];
        }
        __syncthreads();
        for (int e = 0; e < 16; e++) {
            int id = e * 256 + tid;
            int r = id >> 6, c2 = id & 63;
            float s = 0.0f;
#pragma unroll 8
            for (int d = 0; d < 64; d++)
                s += WoutL[r * 64 + d] * WvL[d * 64 + c2];
            P[h * 4096 + id] = s;
        }
    } else {
        const int h = blk - 4;
        float* WqL = WL;                 // [d][c] 64x64
        float* WkL = WL + 4096;          // [d][c2] 64x64
        for (int i = tid; i < 4096; i += 256) {
            int d = i >> 6, cc = i & 63;
            WqL[i] = Wq[(h * 64 + d) * 64 + cc];
            WkL[i] = Wk[(h * 64 + d) * 64 + cc];
        }
        __syncthreads();
        for (int e = 0; e < 16; e++) {
            int id = e * 256 + tid;      // id = c*64 + c2
            int c = id >> 6, c2 = id & 63;
            float s = 0.0f;
#pragma unroll 8
            for (int d = 0; d < 64; d++)
                s += WqL[d * 64 + c] * WkL[d * 64 + c2];
            MS[(size_t)id * 4 + h] = (f16)s;
        }
    }
}

// ---------------------------------------------------------------------------
// k_gram v3: as proven R7/R15 (K=256/block, 8 waves, dbuf LDS), but the logit
// epilogue gathers M from an LDS-staged compact f16 MS table (32 KB) instead
// of 151 MB of per-thread L2 MX reads. grid 256.
// ---------------------------------------------------------------------------
__global__ __launch_bounds__(512, 2) void k_gram(const float* __restrict__ feat,
                                                 const f16x4* __restrict__ MS,
                                                 float* __restrict__ pl) {
    const int kc  = blockIdx.x & (NCHG - 1);
    const int b   = blockIdx.x >> 5;
    const int n0  = kc * 256;
    const int tid = threadIdx.x;
    const int wid = tid >> 6, lane = tid & 63;
    const int l15 = lane & 15, l4 = lane >> 4;
    const int qd = wid & 3, strip = wid >> 2;
    const int qp = (qd >> 1) * 96 + strip * 48;
    const int qq = (qd & 1) * 96;

    __shared__ char smem[77184];         // Tbuf[2] (49152) UNION SRED[8][36][67]
    __shared__ float fin[8][36];
    __shared__ f16x4 MSL[4096];          // compact M table, 32 KB
    char* T0 = smem;
    char* T1 = smem + 24576;
    float (*SRED)[36][67] = (float (*)[36][67])smem;

    const float* fb = feat + (size_t)b * CHN * NPTS * 3;
    const int tc = tid >> 4;
    const int g4 = (tid & 15) * 4;
    const int g8 = (tid & 15) * 8;

    // stage MS -> LDS (32 KB, coalesced; source is L2-broadcast-hot)
    for (int i = tid; i < 4096; i += 512)
        MSL[i] = MS[i];

    f32x4 acc[3][6];
#pragma unroll
    for (int i = 0; i < 3; i++)
#pragma unroll
        for (int j = 0; j < 6; j++) acc[i][j] = (f32x4){0.f, 0.f, 0.f, 0.f};

    float4 SA[2][3], SB[2][3];

#define G_LOADS(S, nbase)                                                      \
    {                                                                          \
        _Pragma("unroll")                                                      \
        for (int ti = 0; ti < 2; ti++) {                                       \
            int c = tc + ti * 32;                                              \
            const float* src = fb + ((size_t)c * NPTS + (nbase) + g4) * 3;     \
            S[ti][0] = *(const float4*)(src);                                  \
            S[ti][1] = *(const float4*)(src + 4);                              \
            S[ti][2] = *(const float4*)(src + 8);                              \
        }                                                                      \
    }
#define G_WRITES(S, Tb)                                                        \
    {                                                                          \
        _Pragma("unroll")                                                      \
        for (int ti = 0; ti < 2; ti++) {                                       \
            int c = tc + ti * 32;                                              \
            float v[12] = {S[ti][0].x, S[ti][0].y, S[ti][0].z, S[ti][0].w,     \
                           S[ti][1].x, S[ti][1].y, S[ti][1].z, S[ti][1].w,     \
                           S[ti][2].x, S[ti][2].y, S[ti][2].z, S[ti][2].w};    \
            _Pragma("unroll")                                                  \
            for (int t = 0; t < 3; t++) {                                      \
                int row = c * 3 + t;                                           \
                f16x4 pk = {(f16)v[t], (f16)v[3 + t], (f16)v[6 + t],           \
                            (f16)v[9 + t]};                                    \
                int bo = (row * 128 + g8) ^ ((row & 7) << 4);                  \
                *(f16x4*)((Tb) + bo) = pk;                                     \
            }                                                                  \
        }                                                                      \
    }
#define G_COMPUTE(Tb)                                                          \
    {                                                                          \
        _Pragma("unroll")                                                      \
        for (int ks = 0; ks < 2; ks++) {                                       \
            f16x8 af[3], bf[6];                                                \
            _Pragma("unroll")                                                  \
            for (int mt = 0; mt < 3; mt++) {                                   \
                int row = qp + mt * 16 + l15;                                  \
                af[mt] = *(const f16x8*)((Tb) +                                \
                    ((row * 128 + ks * 64 + l4 * 16) ^ ((row & 7) << 4)));     \
            }                                                                  \
            _Pragma("unroll")                                                  \
            for (int nt = 0; nt < 6; nt++) {                                   \
                int row = qq + nt * 16 + l15;                                  \
                bf[nt] = *(const f16x8*)((Tb) +                                \
                    ((row * 128 + ks * 64 + l4 * 16) ^ ((row & 7) << 4)));     \
            }                                                                  \
            _Pragma("unroll")                                                  \
            for (int mt = 0; mt < 3; mt++)                                     \
                _Pragma("unroll")                                              \
                for (int nt = 0; nt < 6; nt++)                                 \
                    acc[mt][nt] = __builtin_amdgcn_mfma_f32_16x16x32_f16(      \
                        af[mt], bf[nt], acc[mt][nt], 0, 0, 0);                 \
        }                                                                      \
    }

    G_LOADS(SA, n0);
    G_WRITES(SA, T0);
    G_LOADS(SB, n0 + 64);
    __syncthreads();
    G_COMPUTE(T0); G_WRITES(SB, T1); G_LOADS(SA, n0 + 128);
    __syncthreads();
    G_COMPUTE(T1); G_WRITES(SA, T0); G_LOADS(SB, n0 + 192);
    __syncthreads();
    G_COMPUTE(T0); G_WRITES(SB, T1);
    __syncthreads();
    G_COMPUTE(T1);
    __syncthreads();

    // ---- logit contraction from LDS MS table ----
    int c2v[6];
#pragma unroll
    for (int nt = 0; nt < 6; nt++)
        c2v[nt] = (qq + l15 + nt * 16) / 3;

    float l[36];
#pragma unroll
    for (int i = 0; i < 36; i++) l[i] = 0.0f;
#pragma unroll
    for (int mt = 0; mt < 3; mt++) {
#pragma unroll
        for (int r = 0; r < 4; r++) {
            int p = qp + mt * 16 + l4 * 4 + r;
            int c = p / 3;
            const f16x4* mrow = &MSL[c * 64];
#pragma unroll
            for (int nt = 0; nt < 6; nt++) {
                f16x4 ms = mrow[c2v[nt]];       // 8B LDS read, heavy broadcast
                float g = acc[mt][nt][r];
                const int ts = ((mt + r) % 3) * 3 + (nt % 3);
                l[ts]      = fmaf((float)ms[0], g, l[ts]);
                l[9 + ts]  = fmaf((float)ms[1], g, l[9 + ts]);
                l[18 + ts] = fmaf((float)ms[2], g, l[18 + ts]);
                l[27 + ts] = fmaf((float)ms[3], g, l[27 + ts]);
            }
        }
    }
    const int pt = l4 % 3, ps = l15 % 3;
    int rowmap[9];
#pragma unroll
    for (int tt = 0; tt < 3; tt++)
#pragma unroll
        for (int ss = 0; ss < 3; ss++)
            rowmap[tt * 3 + ss] = ((tt + pt) % 3) * 3 + ((ss + ps) % 3);
#pragma unroll
    for (int h = 0; h < 4; h++)
#pragma unroll
        for (int i9 = 0; i9 < 9; i9++)
            SRED[wid][h * 9 + rowmap[i9]][lane] = l[h * 9 + i9];
    __syncthreads();
    if (tid < 288) {
        int w = tid / 36, row = tid - (tid / 36) * 36;
        float s = 0.0f;
#pragma unroll 8
        for (int col = 0; col < 64; col++) s += SRED[w][row][col];
        fin[w][row] = s;
    }
    __syncthreads();
    if (tid < 36) {
        float s = 0.0f;
#pragma unroll
        for (int w = 0; w < 8; w++) s += fin[w][tid];
        pl[(size_t)(b * NCHG + kc) * 36 + tid] = s;
    }
#undef G_LOADS
#undef G_WRITES
#undef G_COMPUTE
}

// ---------------------------------------------------------------------------
// k_abig: fused softmax + Ab build, identity folded.  (R15, unchanged)
// ---------------------------------------------------------------------------
__global__ __launch_bounds__(256) void k_abig(const float* __restrict__ pl,
                                              const float* __restrict__ P,
                                              f16* __restrict__ Ab) {
    const int blk = blockIdx.x;                // 1152 = 8 b x 144
    const int b   = blk / 144;
    const int tid = threadIdx.x;
    __shared__ float ls[36], wsm[36];
    if (tid < 36) {
        float s = 0.0f;
        for (int k = 0; k < NCHG; k++)
            s += pl[(size_t)(b * NCHG + k) * 36 + tid];
        ls[tid] = s * 0.07216878364870322f;    // 1/sqrt(192)
    }
    __syncthreads();
    if (tid < 36) {
        int base = (tid / 3) * 3;
        float z0 = ls[base], z1 = ls[base + 1], z2 = ls[base + 2];
        float mx = fmaxf(z0, fmaxf(z1, z2));
        float e0 = expf(z0 - mx), e1 = expf(z1 - mx), e2 = expf(z2 - mx);
        wsm[tid] = expf(ls[tid] - mx) / (e0 + e1 + e2);
    }
    __syncthreads();

    int i  = blk * 256 + tid;
    int rr = i - b * GG;
    int p2 = rr / P2, q2 = rr - p2 * P2;
    int o = p2 / 3, t = p2 - 3 * (p2 / 3);
    int c = q2 / 3, s = q2 - 3 * (q2 / 3);
    float acc = (p2 == q2) ? 1.0f : 0.0f;      // identity folded
#pragma unroll
    for (int h = 0; h < 4; h++)
        acc = fmaf(wsm[h * 9 + t * 3 + s], P[h * 4096 + o * 64 + c], acc);
    Ab[i] = (f16)acc;
}

// ---------------------------------------------------------------------------
// k_apply v5 (ground-truth ~19.7 us, near BW floor): out = (I+Abig)*X via LDS
// out-tile, epilogue in two 32-pt rounds, LDS 25.6 KB. grid 1024. (unchanged)
// ---------------------------------------------------------------------------
__global__ __launch_bounds__(256, 4) void k_apply(const float* __restrict__ feat,
                                                  const f16* __restrict__ Ab,
                                                  float* __restrict__ out) {
    const int nb  = blockIdx.x & 127;
    const int b   = blockIdx.x >> 7;
    const int n0  = nb * 64;
    const int tid = threadIdx.x;
    const int wid = tid >> 6, lane = tid & 63;
    const int l15 = lane & 15, l4 = lane >> 4;

    __shared__ char lds[25600];          // X: 64 x 400B  then  OT-half: 64 x 400B

    const float* fb = feat + (size_t)b * CHN * NPTS * 3;
    const f16*   A  = Ab + (size_t)b * GG;
    float*       ob = out + (size_t)b * CHN * NPTS * 3;

    // ---- phase 0: stage X[nn][q2] fp16 (row stride 400 B) ----
    {
        float4 S[12];
#pragma unroll
        for (int i = 0; i < 12; i++) {
            int idx = tid + i * 256;
            int c = idx / 48, j = idx - (idx / 48) * 48;
            S[i] = *(const float4*)(fb + ((size_t)c * NPTS + n0) * 3 + j * 4);
        }
#pragma unroll
        for (int i = 0; i < 12; i++) {
            int idx = tid + i * 256;
            int c = idx / 48, j = idx - (idx / 48) * 48;
            float vv[4] = {S[i].x, S[i].y, S[i].z, S[i].w};
#pragma unroll
            for (int u = 0; u < 4; u++) {
                int e = j * 4 + u, nn = e / 3, s = e - 3 * (e / 3);
                *(f16*)(lds + nn * 400 + (c * 3 + s) * 2) = (f16)vv[u];
            }
        }
    }
    __syncthreads();

    // ---- phase 1: MFMA with 2-deep pipelined A-fragment loads ----
    f32x4 acc[3][4];
#pragma unroll
    for (int i = 0; i < 3; i++)
#pragma unroll
        for (int j = 0; j < 4; j++) acc[i][j] = (f32x4){0.f, 0.f, 0.f, 0.f};

    f16x8 afA[3], afB[3];
    const int prow = wid * 48 + l15;

#define LOAD_AF(dst, ks)                                                       \
    {                                                                          \
        _Pragma("unroll")                                                      \
        for (int mt = 0; mt < 3; mt++)                                         \
            dst[mt] = *(const f16x8*)(A + (size_t)(prow + mt * 16) * P2        \
                                        + (ks) * 32 + l4 * 8);                 \
    }
#define DO_MFMA(src, ks)                                                       \
    {                                                                          \
        f16x8 bf[4];                                                           \
        _Pragma("unroll")                                                      \
        for (int nt = 0; nt < 4; nt++) {                                       \
            int nl = nt * 16 + l15;                                            \
            bf[nt] = *(const f16x8*)(lds + nl * 400 + (ks) * 64 + l4 * 16);    \
        }                                                                      \
        _Pragma("unroll")                                                      \
        for (int mt = 0; mt < 3; mt++)                                         \
            _Pragma("unroll")                                                  \
            for (int nt = 0; nt < 4; nt++)                                     \
                acc[mt][nt] = __builtin_amdgcn_mfma_f32_16x16x32_f16(          \
                    src[mt], bf[nt], acc[mt][nt], 0, 0, 0);                    \
    }

    LOAD_AF(afA, 0);
    LOAD_AF(afB, 1); DO_MFMA(afA, 0);
    LOAD_AF(afA, 2); DO_MFMA(afB, 1);
    LOAD_AF(afB, 3); DO_MFMA(afA, 2);
    LOAD_AF(afA, 4); DO_MFMA(afB, 3);
    LOAD_AF(afB, 5); DO_MFMA(afA, 4);
    DO_MFMA(afB, 5);
#undef LOAD_AF
#undef DO_MFMA

    __syncthreads();                     // X dead; OT takes over the LDS

    // ---- phases 2+3, two rounds of 32 points each ----
#pragma unroll
    for (int rnd = 0; rnd < 2; rnd++) {
#pragma unroll
        for (int mt = 0; mt < 3; mt++) {
#pragma unroll
            for (int r = 0; r < 4; r++) {
                int p2 = wid * 48 + mt * 16 + l4 * 4 + r;
                int o = p2 / 3, t = p2 - 3 * (p2 / 3);
#pragma unroll
                for (int ntl = 0; ntl < 2; ntl++) {
                    int nnl = ntl * 16 + l15;
                    *(float*)(lds + o * 400 + (nnl * 3 + t) * 4)
                        = acc[mt][rnd * 2 + ntl][r];
                }
            }
        }
        __syncthreads();
#pragma unroll
        for (int k = 0; k < 6; k++) {
            int fid = k * 256 + tid;
            int o = fid / 24, w = fid - (fid / 24) * 24;
            float4 v = *(const float4*)(lds + o * 400 + w * 16);
            *(float4*)(ob + ((size_t)o * NPTS + n0 + rnd * 32) * 3 + w * 4) = v;
        }
        __syncthreads();
    }
}

extern "C" void kernel_launch(void* const* d_in, const int* in_sizes, int n_in,
                              void* d_out, int out_size, void* d_ws, size_t ws_size,
                              hipStream_t stream) {
    const float* feat = (const float*)d_in[0];
    const float* Wq   = (const float*)d_in[2];
    const float* Wk   = (const float*)d_in[3];
    const float* Wv   = (const float*)d_in[4];
    const float* Wout = (const float*)d_in[5];
    float* out = (float*)d_out;

    char* w8 = (char*)d_ws;                    // total ws use: ~725 KB
    f16*   Ab = (f16*)w8;                      //   589,824 B
    float* P  = (float*)(w8 + 589824);         //    65,536 B
    f16*   MS = (f16*)(w8 + 655360);           //    32,768 B (f16x4 per (c,c2))
    float* pl = (float*)(w8 + 688128);         //    36,864 B

    k_w    <<<8,            256, 0, stream>>>(Wq, Wk, Wv, Wout, P, MS);
    k_gram <<<BATCH * NCHG, 512, 0, stream>>>(feat, (const f16x4*)MS, pl);
    k_abig <<<1152,         256, 0, stream>>>(pl, P, Ab);
    k_apply<<<1024,         256, 0, stream>>>(feat, Ab, out);
}